// Round 1
// baseline (686.975 us; speedup 1.0000x reference)
//
#include <hip/hip_runtime.h>
#include <hip/hip_bf16.h>
#include <hip/hip_fp16.h>
#include <math.h>

typedef __hip_bfloat16 bf16;
typedef __attribute__((ext_vector_type(8))) short short8;   // 8 bf16 / 8 f16 (16 B)
typedef __attribute__((ext_vector_type(4))) float f32x4;    // MFMA C/D frag

union UB { short8 v; bf16 e[8]; };
union UH { short8 v; __half e[8]; };

// ---------------- helpers ----------------
__device__ __forceinline__ float wred(float v) {
  #pragma unroll
  for (int o = 32; o > 0; o >>= 1) v += __shfl_xor(v, o, 64);
  return v;
}
__device__ __forceinline__ float sigf(float x) { return 1.f / (1.f + expf(-x)); }

__device__ __forceinline__ void gl_lds16(const bf16* g, const bf16* lds) {
  __builtin_amdgcn_global_load_lds((const __attribute__((address_space(1))) void*)g,
                                   (__attribute__((address_space(3))) void*)lds,
                                   16, 0, 0);
}
__device__ __forceinline__ f32x4 mfma16(short8 a, short8 b, f32x4 c) {
  return __builtin_amdgcn_mfma_f32_16x16x32_bf16(a, b, c, 0, 0, 0);
}

// ---- merged batch GEMM: xzrp + xcp, K=512, line-coalesced epilogue ----
__global__ __launch_bounds__(256, 2)
void gemmx(const bf16* __restrict__ A, const bf16* __restrict__ Wxzrt,
           const bf16* __restrict__ Wxct, const float* __restrict__ b_zr,
           const float* __restrict__ b_c, bf16* __restrict__ xzrp,
           bf16* __restrict__ xcp)
{
  __shared__ __align__(16) char smem[34816];
  bf16* As = (bf16*)smem;
  bf16* Bs = (bf16*)(smem + 16384);
  __half* Ts = (__half*)smem;

  const int tid  = threadIdx.x;
  const int wave = tid >> 6, lane = tid & 63;
  const int lm = lane & 15, q = lane >> 4;
  const int brow = blockIdx.x, bcol = blockIdx.y;
  const int wr = (wave >> 1) * 64, wc = (wave & 1) * 64;
  const int srow = lane >> 3, sslot = lane & 7;

  const bf16* Bt; const float* bias; bf16* C; int ldc, colbase;
  if (bcol < 8) { Bt = Wxzrt + (size_t)bcol * 128 * 512; bias = b_zr; C = xzrp; ldc = 1024; colbase = bcol * 128; }
  else          { Bt = Wxct + (size_t)(bcol - 8) * 128 * 512; bias = b_c; C = xcp; ldc = 512; colbase = (bcol - 8) * 128; }

  f32x4 acc[4][4];
  #pragma unroll
  for (int i = 0; i < 4; ++i)
    #pragma unroll
    for (int j = 0; j < 4; ++j) acc[i][j] = (f32x4){0.f, 0.f, 0.f, 0.f};

  for (int kb = 0; kb < 512; kb += 64) {
    #pragma unroll
    for (int j = 0; j < 4; ++j) {
      int ml = wave * 32 + j * 8 + srow;
      int cg = sslot ^ (ml & 7);
      gl_lds16(A + (size_t)(brow * 128 + ml) * 512 + kb + cg * 8, As + (wave * 4 + j) * 512);
      gl_lds16(Bt + (size_t)ml * 512 + kb + cg * 8, Bs + (wave * 4 + j) * 512);
    }
    __syncthreads();
    #pragma unroll
    for (int ks = 0; ks < 2; ++ks) {
      short8 af[4], bfr[4];
      #pragma unroll
      for (int i = 0; i < 4; ++i) {
        int cg = ks * 4 + q;
        int ml = wr + i * 16 + lm;
        af[i]  = *(const short8*)(As + ml * 64 + ((cg ^ (ml & 7)) * 8));
        int nl = wc + i * 16 + lm;
        bfr[i] = *(const short8*)(Bs + nl * 64 + ((cg ^ (nl & 7)) * 8));
      }
      #pragma unroll
      for (int i = 0; i < 4; ++i)
        #pragma unroll
        for (int j = 0; j < 4; ++j)
          acc[i][j] = mfma16(af[i], bfr[j], acc[i][j]);
    }
    __syncthreads();
  }
  #pragma unroll
  for (int i = 0; i < 4; ++i)
    #pragma unroll
    for (int j = 0; j < 4; ++j) {
      int col = wc + j * 16 + lm;
      float bv = bias[colbase + col];
      #pragma unroll
      for (int p = 0; p < 4; ++p)
        Ts[(wr + i * 16 + q * 4 + p) * 136 + col] = __float2half(acc[i][j][p] + bv);
    }
  __syncthreads();
  int rg = tid >> 4, cl = tid & 15;
  #pragma unroll
  for (int v = 0; v < 8; ++v) {
    int row = v * 16 + rg;
    UH t; t.v = *(const short8*)(Ts + row * 136 + cl * 8);
    UB o;
    #pragma unroll
    for (int e = 0; e < 8; ++e) o.e[e] = __float2bfloat16(__half2float(t.e[e]));
    *(short8*)(C + (size_t)(brow * 128 + row) * ldc + colbase + cl * 8) = o.v;
  }
}

// ---- GCN batch GEMM: grid (256, 2, 2), line-coalesced epilogue ----
__global__ __launch_bounds__(256, 2)
void gcnk(const float* __restrict__ Ag, const float* __restrict__ Agi,
          const bf16* __restrict__ Wgt, const float* __restrict__ bias,
          bf16* __restrict__ out)
{
  __shared__ __align__(16) char smem[34816];
  bf16* As = (bf16*)smem;
  bf16* Bs = (bf16*)(smem + 16384);
  __half* Ts = (__half*)smem;

  const int tid  = threadIdx.x;
  const int wave = tid >> 6, lane = tid & 63;
  const int lm = lane & 15, q = lane >> 4;
  const int brow = blockIdx.x, bcol = blockIdx.y;
  const int z = blockIdx.z, cout = z * 256;
  const float* A = z ? Agi : Ag;
  const int wr = (wave >> 1) * 64, wc = (wave & 1) * 64;
  const int srow = lane >> 3, sslot = lane & 7;

  f32x4 acc[4][4];
  #pragma unroll
  for (int i = 0; i < 4; ++i)
    #pragma unroll
    for (int j = 0; j < 4; ++j) acc[i][j] = (f32x4){0.f, 0.f, 0.f, 0.f};

  for (int kb = 0; kb < 128; kb += 64) {
    #pragma unroll
    for (int j = 0; j < 4; ++j) {
      int ml = wave * 32 + j * 8 + srow;
      int cg = sslot ^ (ml & 7);
      const float* src = A + (size_t)(brow * 128 + ml) * 128 + kb + cg * 8;
      bf16 tmp[8];
      #pragma unroll
      for (int e = 0; e < 8; ++e) tmp[e] = __float2bfloat16(src[e]);
      *(short8*)(As + ml * 64 + sslot * 8) = *(const short8*)tmp;
      gl_lds16(Wgt + (size_t)(bcol * 128 + ml) * 128 + kb + cg * 8,
               Bs + (wave * 4 + j) * 512);
    }
    __syncthreads();
    #pragma unroll
    for (int ks = 0; ks < 2; ++ks) {
      short8 af[4], bfr[4];
      #pragma unroll
      for (int i = 0; i < 4; ++i) {
        int cg = ks * 4 + q;
        int ml = wr + i * 16 + lm;
        af[i]  = *(const short8*)(As + ml * 64 + ((cg ^ (ml & 7)) * 8));
        int nl = wc + i * 16 + lm;
        bfr[i] = *(const short8*)(Bs + nl * 64 + ((cg ^ (nl & 7)) * 8));
      }
      #pragma unroll
      for (int i = 0; i < 4; ++i)
        #pragma unroll
        for (int j = 0; j < 4; ++j)
          acc[i][j] = mfma16(af[i], bfr[j], acc[i][j]);
    }
    __syncthreads();
  }
  #pragma unroll
  for (int i = 0; i < 4; ++i)
    #pragma unroll
    for (int j = 0; j < 4; ++j) {
      int col = wc + j * 16 + lm;
      float bv = bias[bcol * 128 + col];
      #pragma unroll
      for (int p = 0; p < 4; ++p)
        Ts[(wr + i * 16 + q * 4 + p) * 136 + col] = __float2half(acc[i][j][p] + bv);
    }
  __syncthreads();
  int rg = tid >> 4, cl = tid & 15;
  #pragma unroll
  for (int v = 0; v < 8; ++v) {
    int row = v * 16 + rg;
    UH t; t.v = *(const short8*)(Ts + row * 136 + cl * 8);
    UB o;
    #pragma unroll
    for (int e = 0; e < 8; ++e) o.e[e] = __float2bfloat16(fmaxf(__half2float(t.e[e]), 0.f));
    *(short8*)(out + (size_t)(brow * 128 + row) * 512 + cout + bcol * 128 + cl * 8) = o.v;
  }
}

// ---- fused GRU: whole 8-step recurrence in ONE kernel -----------------------
// Row-local recurrence: block owns 32 rows; h/rh/z live in LDS (XOR-swizzled,
// 16B granule). B (weights) read directly from L2 in fragment-linear layout
// (packed by prep): frag(nblk,KS) is 1KB lane-contiguous. No LDS staging for B.
__global__ __launch_bounds__(256, 1)
void grufuse(const bf16* __restrict__ Wzr, const bf16* __restrict__ Wc,
             const bf16* __restrict__ xzrp, const bf16* __restrict__ xcp,
             bf16* __restrict__ hsb)
{
  __shared__ __align__(16) bf16   hls[32 * 512];   // 32KB h state (swizzled)
  __shared__ __align__(16) bf16   rls[32 * 512];   // 32KB r*h     (swizzled)
  __shared__ __align__(16) __half zls[32 * 512];   // 32KB z gate  (swizzled)
  __shared__ __align__(16) __half Ts[32 * 136];    // 8.5KB acc roundtrip

  const int tid  = threadIdx.x;
  const int wave = tid >> 6, lane = tid & 63;
  const int lm = lane & 15, q = lane >> 4;
  const int n0 = blockIdx.x * 32;
  const int prow = tid >> 3, pcs = (tid & 7) * 16;   // pass2: (row, 16-col seg)

  { // h0 = 0
    short8 zz = (short8){0,0,0,0,0,0,0,0};
    #pragma unroll
    for (int i = 0; i < 16; ++i)
      *(short8*)(hls + tid * 128 + i * 8) = zz;
  }
  __syncthreads();

  for (int t = 0; t < 8; ++t) {
    const bf16* xz = xzrp + (size_t)(t * 4096 + n0) * 1024;
    const bf16* xc = xcp  + (size_t)(t * 4096 + n0) * 512;

    // ---- GEMM1: zr = h @ Wh_zr (1024 cols, 8 chunks of 128) ----
    for (int NB = 0; NB < 8; ++NB) {
      // prefetch x-projection chunk early; MFMA phase hides the latency
      UB xv0, xv1;
      xv0.v = *(const short8*)(xz + (size_t)prow * 1024 + NB * 128 + pcs);
      xv1.v = *(const short8*)(xz + (size_t)prow * 1024 + NB * 128 + pcs + 8);

      f32x4 acc[2][2];
      #pragma unroll
      for (int i = 0; i < 2; ++i)
        #pragma unroll
        for (int j = 0; j < 2; ++j) acc[i][j] = (f32x4){0.f, 0.f, 0.f, 0.f};

      if (t) {   // t==0: h==0 -> acc stays 0 (skip 1/8 of weight traffic)
        const int nb0 = NB * 8 + wave * 2;
        const bf16* B0 = Wzr + (size_t)(nb0 * 16) * 512 + lane * 8;
        const bf16* B1 = Wzr + (size_t)((nb0 + 1) * 16) * 512 + lane * 8;
        #pragma unroll
        for (int KS = 0; KS < 16; ++KS) {
          const int s = (((KS * 4 + q) ^ (lm & 7)) * 8);
          short8 a0 = *(const short8*)(hls + lm * 512 + s);
          short8 a1 = *(const short8*)(hls + (16 + lm) * 512 + s);
          short8 b0 = *(const short8*)(B0 + KS * 512);
          short8 b1 = *(const short8*)(B1 + KS * 512);
          acc[0][0] = mfma16(a0, b0, acc[0][0]);
          acc[1][0] = mfma16(a1, b0, acc[1][0]);
          acc[0][1] = mfma16(a0, b1, acc[0][1]);
          acc[1][1] = mfma16(a1, b1, acc[1][1]);
        }
      }
      #pragma unroll
      for (int rf = 0; rf < 2; ++rf)
        #pragma unroll
        for (int nf = 0; nf < 2; ++nf)
          #pragma unroll
          for (int p = 0; p < 4; ++p)
            Ts[(rf * 16 + q * 4 + p) * 136 + wave * 32 + nf * 16 + lm] =
              __float2half(acc[rf][nf][p]);
      __syncthreads();
      {
        UH t0, t1;
        t0.v = *(const short8*)(Ts + prow * 136 + pcs);
        t1.v = *(const short8*)(Ts + prow * 136 + pcs + 8);
        if (NB < 4) {                       // z gate -> zls
          int zc = NB * 128 + pcs;
          UH o0, o1;
          #pragma unroll
          for (int e = 0; e < 8; ++e) {
            o0.e[e] = __float2half(sigf(__half2float(t0.e[e]) + (float)xv0.e[e]));
            o1.e[e] = __float2half(sigf(__half2float(t1.e[e]) + (float)xv1.e[e]));
          }
          *(short8*)(zls + prow * 512 + ((((zc >> 3)    ) ^ (prow & 7)) << 3)) = o0.v;
          *(short8*)(zls + prow * 512 + ((((zc >> 3) + 1) ^ (prow & 7)) << 3)) = o1.v;
        } else {                            // r gate * h -> rls
          int rc = NB * 128 + pcs - 512;
          UB h0, h1, o0, o1;
          h0.v = *(const short8*)(hls + prow * 512 + ((((rc >> 3)    ) ^ (prow & 7)) << 3));
          h1.v = *(const short8*)(hls + prow * 512 + ((((rc >> 3) + 1) ^ (prow & 7)) << 3));
          #pragma unroll
          for (int e = 0; e < 8; ++e) {
            float r0 = sigf(__half2float(t0.e[e]) + (float)xv0.e[e]);
            float r1 = sigf(__half2float(t1.e[e]) + (float)xv1.e[e]);
            o0.e[e] = __float2bfloat16(r0 * (float)h0.e[e]);
            o1.e[e] = __float2bfloat16(r1 * (float)h1.e[e]);
          }
          *(short8*)(rls + prow * 512 + ((((rc >> 3)    ) ^ (prow & 7)) << 3)) = o0.v;
          *(short8*)(rls + prow * 512 + ((((rc >> 3) + 1) ^ (prow & 7)) << 3)) = o1.v;
        }
      }
      __syncthreads();
    }

    // ---- GEMM2: c = (r*h) @ Wh_c (512 cols, 4 chunks); h update ----
    for (int NB = 0; NB < 4; ++NB) {
      UB xv0, xv1;
      xv0.v = *(const short8*)(xc + (size_t)prow * 512 + NB * 128 + pcs);
      xv1.v = *(const short8*)(xc + (size_t)prow * 512 + NB * 128 + pcs + 8);

      f32x4 acc[2][2];
      #pragma unroll
      for (int i = 0; i < 2; ++i)
        #pragma unroll
        for (int j = 0; j < 2; ++j) acc[i][j] = (f32x4){0.f, 0.f, 0.f, 0.f};

      if (t) {   // t==0: rh==0
        const int nb0 = NB * 8 + wave * 2;
        const bf16* B0 = Wc + (size_t)(nb0 * 16) * 512 + lane * 8;
        const bf16* B1 = Wc + (size_t)((nb0 + 1) * 16) * 512 + lane * 8;
        #pragma unroll
        for (int KS = 0; KS < 16; ++KS) {
          const int s = (((KS * 4 + q) ^ (lm & 7)) * 8);
          short8 a0 = *(const short8*)(rls + lm * 512 + s);
          short8 a1 = *(const short8*)(rls + (16 + lm) * 512 + s);
          short8 b0 = *(const short8*)(B0 + KS * 512);
          short8 b1 = *(const short8*)(B1 + KS * 512);
          acc[0][0] = mfma16(a0, b0, acc[0][0]);
          acc[1][0] = mfma16(a1, b0, acc[1][0]);
          acc[0][1] = mfma16(a0, b1, acc[0][1]);
          acc[1][1] = mfma16(a1, b1, acc[1][1]);
        }
      }
      #pragma unroll
      for (int rf = 0; rf < 2; ++rf)
        #pragma unroll
        for (int nf = 0; nf < 2; ++nf)
          #pragma unroll
          for (int p = 0; p < 4; ++p)
            Ts[(rf * 16 + q * 4 + p) * 136 + wave * 32 + nf * 16 + lm] =
              __float2half(acc[rf][nf][p]);
      __syncthreads();
      {
        int col = NB * 128 + pcs;
        int s0 = (((col >> 3)    ) ^ (prow & 7)) << 3;
        int s1 = (((col >> 3) + 1) ^ (prow & 7)) << 3;
        UH t0, t1, z0, z1;
        t0.v = *(const short8*)(Ts + prow * 136 + pcs);
        t1.v = *(const short8*)(Ts + prow * 136 + pcs + 8);
        z0.v = *(const short8*)(zls + prow * 512 + s0);
        z1.v = *(const short8*)(zls + prow * 512 + s1);
        UB h0, h1, o0, o1;
        h0.v = *(const short8*)(hls + prow * 512 + s0);
        h1.v = *(const short8*)(hls + prow * 512 + s1);
        #pragma unroll
        for (int e = 0; e < 8; ++e) {
          float c0 = tanhf(__half2float(t0.e[e]) + (float)xv0.e[e]);
          float c1 = tanhf(__half2float(t1.e[e]) + (float)xv1.e[e]);
          float za = __half2float(z0.e[e]);
          float zb = __half2float(z1.e[e]);
          o0.e[e] = __float2bfloat16(za * (float)h0.e[e] + (1.f - za) * c0);
          o1.e[e] = __float2bfloat16(zb * (float)h1.e[e] + (1.f - zb) * c1);
        }
        *(short8*)(hls + prow * 512 + s0) = o0.v;
        *(short8*)(hls + prow * 512 + s1) = o1.v;
        if (t == 7) {
          *(short8*)(hsb + (size_t)(n0 + prow) * 512 + col)     = o0.v;
          *(short8*)(hsb + (size_t)(n0 + prow) * 512 + col + 8) = o1.v;
        }
      }
      __syncthreads();
    }
  }
}

// ---- one-shot weight transpose/convert ----
// Wh_zr / Wh_c now packed in MFMA-fragment-linear layout for grufuse:
//   element (n,k) -> ((n>>4)*16 + (k>>5))*512 + ((k>>3)&3)*128 + (n&15)*8 + (k&7)
__global__ void prep(const float* __restrict__ Wh_zr, const float* __restrict__ Wh_c,
                     const float* __restrict__ Wx_zr, const float* __restrict__ Wx_c,
                     const float* __restrict__ W_gcn,
                     bf16* __restrict__ Whzrt, bf16* __restrict__ Whct,
                     bf16* __restrict__ Wxzrt, bf16* __restrict__ Wxct,
                     bf16* __restrict__ Wgt) {
  int i = blockIdx.x * 256 + threadIdx.x;   // grid 6272
  if (i < 524288) {
    int n = i >> 9, k = i & 511;
    int off = ((n >> 4) * 16 + (k >> 5)) * 512 + ((k >> 3) & 3) * 128 + (n & 15) * 8 + (k & 7);
    Whzrt[off] = __float2bfloat16(Wh_zr[(size_t)k * 1024 + n]);
  } else if (i < 786432) {
    int j = i - 524288; int n = j >> 9, k = j & 511;
    int off = ((n >> 4) * 16 + (k >> 5)) * 512 + ((k >> 3) & 3) * 128 + (n & 15) * 8 + (k & 7);
    Whct[off] = __float2bfloat16(Wh_c[(size_t)k * 512 + n]);
  } else if (i < 1310720) {
    int j = i - 786432; int n = j >> 9, k = j & 511;
    Wxzrt[j] = __float2bfloat16(Wx_zr[(size_t)k * 1024 + n]);
  } else if (i < 1572864) {
    int j = i - 1310720; int n = j >> 9, k = j & 511;
    Wxct[j] = __float2bfloat16(Wx_c[(size_t)k * 512 + n]);
  } else {
    int j = i - 1572864; int n = j >> 7, k = j & 127;
    Wgt[j] = __float2bfloat16(W_gcn[(size_t)k * 256 + n]);
  }
}

// ---- epilogue kernels (green since R13) ----
__global__ void norm_lvec(const bf16* __restrict__ hsb, const float* __restrict__ Wl,
                          const float* __restrict__ bl, const float* __restrict__ hv,
                          bf16* __restrict__ Htrb, float* __restrict__ lv,
                          float* __restrict__ hn) {
  int w = threadIdx.x >> 6, lane = threadIdx.x & 63;
  if (blockIdx.x == 1024) {
    float x[8], ss = 0.f;
    #pragma unroll
    for (int j = 0; j < 8; ++j) { x[j] = hv[w * 512 + lane * 8 + j]; ss += x[j] * x[j]; }
    ss = wred(ss);
    float inv = 1.f / fmaxf(sqrtf(ss), 1e-12f);
    #pragma unroll
    for (int j = 0; j < 8; ++j) hn[w * 512 + lane * 8 + j] = x[j] * inv;
    return;
  }
  int n = blockIdx.x * 4 + w;
  float x[8], ss = 0.f;
  #pragma unroll
  for (int j = 0; j < 8; ++j) {
    x[j] = (float)hsb[(size_t)n * 512 + lane * 8 + j];
    ss += x[j] * x[j];
  }
  ss = wred(ss);
  float inv = 1.f / fmaxf(sqrtf(ss), 1e-12f);
  float dot = 0.f;
  #pragma unroll
  for (int j = 0; j < 8; ++j) {
    float vv = x[j] * inv;
    Htrb[(size_t)n * 512 + lane * 8 + j] = __float2bfloat16(vv);
    dot += vv * Wl[lane * 8 + j];
  }
  dot = wred(dot);
  if (lane == 0) lv[n] = sigf(dot + bl[0]);
}

__global__ void htf(const bf16* __restrict__ Htrb, const float* __restrict__ xf,
                    const float* __restrict__ Wc, const float* __restrict__ bc,
                    const float* __restrict__ lv, float* __restrict__ v) {
  __shared__ float fin_s[4][64];
  int ch = blockIdx.x;                              // grid 64, block 512
  int d = threadIdx.x;
  int n0 = ch * 64;
  if (d < 256) {
    int t = d >> 6, i = d & 63, n = n0 + i;
    float g = bc[t];
    #pragma unroll
    for (int tt = 0; tt < 5; ++tt) g += xf[tt * 4096 + n] * Wc[tt * 4 + t];
    fin_s[t][i] = lv[n] * g;
  }
  __syncthreads();
  float s0 = 0.f, s1 = 0.f, s2 = 0.f, s3 = 0.f;
  for (int i = 0; i < 64; ++i) {
    float hv = (float)Htrb[(size_t)(n0 + i) * 512 + d];
    s0 += hv * fin_s[0][i];
    s1 += hv * fin_s[1][i];
    s2 += hv * fin_s[2][i];
    s3 += hv * fin_s[3][i];
  }
  atomicAdd(&v[d], s0);
  atomicAdd(&v[512 + d], s1);
  atomicAdd(&v[1024 + d], s2);
  atomicAdd(&v[1536 + d], s3);
}

__global__ void attk(const bf16* __restrict__ Htrb, const float* __restrict__ v,
                     float* __restrict__ out) {
  int w = threadIdx.x >> 6, lane = threadIdx.x & 63;
  int n = blockIdx.x * 4 + w;
  float x[8];
  #pragma unroll
  for (int j = 0; j < 8; ++j) x[j] = (float)Htrb[(size_t)n * 512 + lane * 8 + j];
  #pragma unroll
  for (int t = 0; t < 4; ++t) {
    float s = 0.f;
    #pragma unroll
    for (int j = 0; j < 8; ++j) s += x[j] * v[t * 512 + lane * 8 + j];
    s = wred(s);
    if (lane == 0) out[t * 4096 + n] = s;
  }
}

__global__ void loff(const bf16* __restrict__ Htrb, const float* __restrict__ hn,
                     const int* __restrict__ ty, float* __restrict__ loffp) {
  int w = threadIdx.x >> 6, lane = threadIdx.x & 63;
  int t = blockIdx.y;
  int m = blockIdx.x * 4 + w;
  const int* row = ty + ((size_t)t * 2048 + m) * 18;
  int pi = row[1];
  float p[8], hv[8], c = 0.f;
  #pragma unroll
  for (int j = 0; j < 8; ++j) {
    p[j]  = (float)Htrb[(size_t)pi * 512 + lane * 8 + j];
    hv[j] = hn[t * 512 + lane * 8 + j];
    c += p[j] * hv[j];
  }
  c = wred(c);
  float a[8], sp = 0.f;
  #pragma unroll
  for (int j = 0; j < 8; ++j) { a[j] = p[j] - 2.f * c * hv[j]; sp += a[j] * p[j]; }
  sp = wred(sp);
  float acc = 0.f;
  for (int k = 0; k < 16; ++k) {
    int ni = row[2 + k];
    float sn = 0.f;
    #pragma unroll
    for (int j = 0; j < 8; ++j) sn += a[j] * (float)Htrb[(size_t)ni * 512 + lane * 8 + j];
    sn = wred(sn);
    acc += fmaxf(sn - sp + 0.5f, 0.f);
  }
  __shared__ float sbuf[4];
  if (lane == 0) sbuf[w] = acc;
  __syncthreads();
  if (threadIdx.x == 0)
    loffp[t * 512 + blockIdx.x] = sbuf[0] + sbuf[1] + sbuf[2] + sbuf[3];
}

__global__ void fini(const float* __restrict__ loffp, const float* __restrict__ lv,
                     const float* __restrict__ yl, float* __restrict__ out) {
  int tid = threadIdx.x, w = tid >> 6, lane = tid & 63;
  float s = 0.f, s2 = 0.f;
  for (int i = tid; i < 2048; i += 256) s += loffp[i];
  for (int i = tid; i < 4096; i += 256) {
    float l = lv[i];
    float ym = 0.25f * (yl[i] + yl[4096 + i] + yl[8192 + i] + yl[12288 + i]);
    s2 += fmaxf(l, 0.f) - l * ym + log1pf(expf(-fabsf(l)));
  }
  s = wred(s); s2 = wred(s2);
  __shared__ float sb[4], sb2[4];
  if (lane == 0) { sb[w] = s; sb2[w] = s2; }
  __syncthreads();
  if (tid == 0) {
    out[16384] = (sb[0] + sb[1] + sb[2] + sb[3]) / (4.f * 2048.f * 16.f);
    out[16385] = (sb2[0] + sb2[1] + sb2[2] + sb2[3]) / 4096.f;
  }
}

__global__ void wsprobe(float marker, float* out) {
  if (threadIdx.x == 0) out[0] = marker;
}

// ---------------- launch ----------------
extern "C" void kernel_launch(void* const* d_in, const int* in_sizes, int n_in,
                              void* d_out, int out_size, void* d_ws, size_t ws_size,
                              hipStream_t stream) {
  const float* x_feature   = (const float*)d_in[0];
  const float* x_graph     = (const float*)d_in[1];
  const float* x_graph_inv = (const float*)d_in[2];
  const int*   temp_y      = (const int*)d_in[3];
  const float* is_leaf     = (const float*)d_in[4];
  const float* W_gcn       = (const float*)d_in[5];
  const float* b_gcn       = (const float*)d_in[6];
  const float* Wx_zr       = (const float*)d_in[7];
  const float* Wh_zr       = (const float*)d_in[8];
  const float* b_zr        = (const float*)d_in[9];
  const float* Wx_c        = (const float*)d_in[10];
  const float* Wh_c        = (const float*)d_in[11];
  const float* b_c         = (const float*)d_in[12];
  const float* h_vecs      = (const float*)d_in[13];
  const float* W_leaf      = (const float*)d_in[14];
  const float* b_leaf      = (const float*)d_in[15];
  const float* W_conv      = (const float*)d_in[16];
  const float* b_conv      = (const float*)d_in[17];
  float* out = (float*)d_out;
  (void)in_sizes; (void)n_in; (void)out_size;

  const size_t NEED = 156000000;
  if (ws_size < NEED) {
    wsprobe<<<1, 64, 0, stream>>>(1000.f + (float)(ws_size >> 20), out);
    return;
  }

  char* ws = (char*)d_ws;
  size_t off = 0;
  auto alloc = [&](size_t bytes) -> void* {
    void* p = ws + off;
    off = (off + bytes + 255) & ~(size_t)255;
    return p;
  };
  bf16*   Whzrt = (bf16*)  alloc((size_t)1024 * 512 * 2);
  bf16*   Whct  = (bf16*)  alloc((size_t)512 * 512 * 2);
  bf16*   Wxzrt = (bf16*)  alloc((size_t)1024 * 512 * 2);
  bf16*   Wxct  = (bf16*)  alloc((size_t)512 * 512 * 2);
  bf16*   Wgt   = (bf16*)  alloc((size_t)256 * 128 * 2);
  bf16*   hfin  = (bf16*)  alloc((size_t)32768 * 512 * 2);  // 32 MB
  bf16*   xzrp  = (bf16*)  alloc((size_t)32768 * 1024 * 2); // 64 MB (bias folded)
  bf16*   xcp   = (bf16*)  alloc((size_t)32768 * 512 * 2);  // 32 MB (bias folded)
  bf16*   hsb   = (bf16*)  alloc((size_t)4096 * 512 * 2);
  float*  lv    = (float*) alloc(4096 * 4);
  float*  hn    = (float*) alloc(4 * 512 * 4);
  float*  v     = (float*) alloc(4 * 512 * 4);
  float*  loffp = (float*) alloc(2048 * 4);
  bf16*   Htrb  = hfin;   // overlay: hfin dead after gemmx consumes it

  hipMemsetAsync(v, 0, 4 * 512 * 4, stream);

  prep<<<6272, 256, 0, stream>>>(Wh_zr, Wh_c, Wx_zr, Wx_c, W_gcn,
                                 Whzrt, Whct, Wxzrt, Wxct, Wgt);
  gcnk<<<dim3(256, 2, 2), 256, 0, stream>>>(x_graph, x_graph_inv, Wgt, b_gcn, hfin);
  gemmx<<<dim3(256, 12), 256, 0, stream>>>(hfin, Wxzrt, Wxct, b_zr, b_c, xzrp, xcp);

  // entire 8-step GRU in one kernel: h resident in LDS, weights from L2
  grufuse<<<128, 256, 0, stream>>>(Whzrt, Whct, xzrp, xcp, hsb);

  norm_lvec<<<1025, 256, 0, stream>>>(hsb, W_leaf, b_leaf, h_vecs, Htrb, lv, hn);
  htf<<<64, 512, 0, stream>>>(Htrb, x_feature, W_conv, b_conv, lv, v);
  attk<<<1024, 256, 0, stream>>>(Htrb, v, out);
  loff<<<dim3(512, 4), 256, 0, stream>>>(Htrb, hn, temp_y, loffp);
  fini<<<1, 256, 0, stream>>>(loffp, lv, is_leaf, out);
}

// Round 2
// 520.670 us; speedup vs baseline: 1.3194x; 1.3194x over previous
//
#include <hip/hip_runtime.h>
#include <hip/hip_bf16.h>
#include <hip/hip_fp16.h>
#include <math.h>

typedef __hip_bfloat16 bf16;
typedef __attribute__((ext_vector_type(8))) short short8;   // 8 bf16 / 8 f16 (16 B)
typedef __attribute__((ext_vector_type(4))) float f32x4;    // MFMA C/D frag

union UB { short8 v; bf16 e[8]; };
union UH { short8 v; __half e[8]; };

// ---------------- helpers ----------------
__device__ __forceinline__ float wred(float v) {
  #pragma unroll
  for (int o = 32; o > 0; o >>= 1) v += __shfl_xor(v, o, 64);
  return v;
}
__device__ __forceinline__ float sigf(float x) { return 1.f / (1.f + expf(-x)); }

__device__ __forceinline__ void gl_lds16(const bf16* g, const bf16* lds) {
  __builtin_amdgcn_global_load_lds((const __attribute__((address_space(1))) void*)g,
                                   (__attribute__((address_space(3))) void*)lds,
                                   16, 0, 0);
}
__device__ __forceinline__ f32x4 mfma16(short8 a, short8 b, f32x4 c) {
  return __builtin_amdgcn_mfma_f32_16x16x32_bf16(a, b, c, 0, 0, 0);
}

// ---- merged batch GEMM: xzrp + xcp, K=512, line-coalesced epilogue ----
__global__ __launch_bounds__(256, 2)
void gemmx(const bf16* __restrict__ A, const bf16* __restrict__ Wxzrt,
           const bf16* __restrict__ Wxct, const float* __restrict__ b_zr,
           const float* __restrict__ b_c, bf16* __restrict__ xzrp,
           bf16* __restrict__ xcp)
{
  __shared__ __align__(16) char smem[34816];
  bf16* As = (bf16*)smem;
  bf16* Bs = (bf16*)(smem + 16384);
  __half* Ts = (__half*)smem;

  const int tid  = threadIdx.x;
  const int wave = tid >> 6, lane = tid & 63;
  const int lm = lane & 15, q = lane >> 4;
  const int brow = blockIdx.x, bcol = blockIdx.y;
  const int wr = (wave >> 1) * 64, wc = (wave & 1) * 64;
  const int srow = lane >> 3, sslot = lane & 7;

  const bf16* Bt; const float* bias; bf16* C; int ldc, colbase;
  if (bcol < 8) { Bt = Wxzrt + (size_t)bcol * 128 * 512; bias = b_zr; C = xzrp; ldc = 1024; colbase = bcol * 128; }
  else          { Bt = Wxct + (size_t)(bcol - 8) * 128 * 512; bias = b_c; C = xcp; ldc = 512; colbase = (bcol - 8) * 128; }

  f32x4 acc[4][4];
  #pragma unroll
  for (int i = 0; i < 4; ++i)
    #pragma unroll
    for (int j = 0; j < 4; ++j) acc[i][j] = (f32x4){0.f, 0.f, 0.f, 0.f};

  for (int kb = 0; kb < 512; kb += 64) {
    #pragma unroll
    for (int j = 0; j < 4; ++j) {
      int ml = wave * 32 + j * 8 + srow;
      int cg = sslot ^ (ml & 7);
      gl_lds16(A + (size_t)(brow * 128 + ml) * 512 + kb + cg * 8, As + (wave * 4 + j) * 512);
      gl_lds16(Bt + (size_t)ml * 512 + kb + cg * 8, Bs + (wave * 4 + j) * 512);
    }
    __syncthreads();
    #pragma unroll
    for (int ks = 0; ks < 2; ++ks) {
      short8 af[4], bfr[4];
      #pragma unroll
      for (int i = 0; i < 4; ++i) {
        int cg = ks * 4 + q;
        int ml = wr + i * 16 + lm;
        af[i]  = *(const short8*)(As + ml * 64 + ((cg ^ (ml & 7)) * 8));
        int nl = wc + i * 16 + lm;
        bfr[i] = *(const short8*)(Bs + nl * 64 + ((cg ^ (nl & 7)) * 8));
      }
      #pragma unroll
      for (int i = 0; i < 4; ++i)
        #pragma unroll
        for (int j = 0; j < 4; ++j)
          acc[i][j] = mfma16(af[i], bfr[j], acc[i][j]);
    }
    __syncthreads();
  }
  #pragma unroll
  for (int i = 0; i < 4; ++i)
    #pragma unroll
    for (int j = 0; j < 4; ++j) {
      int col = wc + j * 16 + lm;
      float bv = bias[colbase + col];
      #pragma unroll
      for (int p = 0; p < 4; ++p)
        Ts[(wr + i * 16 + q * 4 + p) * 136 + col] = __float2half(acc[i][j][p] + bv);
    }
  __syncthreads();
  int rg = tid >> 4, cl = tid & 15;
  #pragma unroll
  for (int v = 0; v < 8; ++v) {
    int row = v * 16 + rg;
    UH t; t.v = *(const short8*)(Ts + row * 136 + cl * 8);
    UB o;
    #pragma unroll
    for (int e = 0; e < 8; ++e) o.e[e] = __float2bfloat16(__half2float(t.e[e]));
    *(short8*)(C + (size_t)(brow * 128 + row) * ldc + colbase + cl * 8) = o.v;
  }
}

// ---- GCN batch GEMM: grid (256, 2, 2), line-coalesced epilogue ----
__global__ __launch_bounds__(256, 2)
void gcnk(const float* __restrict__ Ag, const float* __restrict__ Agi,
          const bf16* __restrict__ Wgt, const float* __restrict__ bias,
          bf16* __restrict__ out)
{
  __shared__ __align__(16) char smem[34816];
  bf16* As = (bf16*)smem;
  bf16* Bs = (bf16*)(smem + 16384);
  __half* Ts = (__half*)smem;

  const int tid  = threadIdx.x;
  const int wave = tid >> 6, lane = tid & 63;
  const int lm = lane & 15, q = lane >> 4;
  const int brow = blockIdx.x, bcol = blockIdx.y;
  const int z = blockIdx.z, cout = z * 256;
  const float* A = z ? Agi : Ag;
  const int wr = (wave >> 1) * 64, wc = (wave & 1) * 64;
  const int srow = lane >> 3, sslot = lane & 7;

  f32x4 acc[4][4];
  #pragma unroll
  for (int i = 0; i < 4; ++i)
    #pragma unroll
    for (int j = 0; j < 4; ++j) acc[i][j] = (f32x4){0.f, 0.f, 0.f, 0.f};

  for (int kb = 0; kb < 128; kb += 64) {
    #pragma unroll
    for (int j = 0; j < 4; ++j) {
      int ml = wave * 32 + j * 8 + srow;
      int cg = sslot ^ (ml & 7);
      const float* src = A + (size_t)(brow * 128 + ml) * 128 + kb + cg * 8;
      bf16 tmp[8];
      #pragma unroll
      for (int e = 0; e < 8; ++e) tmp[e] = __float2bfloat16(src[e]);
      *(short8*)(As + ml * 64 + sslot * 8) = *(const short8*)tmp;
      gl_lds16(Wgt + (size_t)(bcol * 128 + ml) * 128 + kb + cg * 8,
               Bs + (wave * 4 + j) * 512);
    }
    __syncthreads();
    #pragma unroll
    for (int ks = 0; ks < 2; ++ks) {
      short8 af[4], bfr[4];
      #pragma unroll
      for (int i = 0; i < 4; ++i) {
        int cg = ks * 4 + q;
        int ml = wr + i * 16 + lm;
        af[i]  = *(const short8*)(As + ml * 64 + ((cg ^ (ml & 7)) * 8));
        int nl = wc + i * 16 + lm;
        bfr[i] = *(const short8*)(Bs + nl * 64 + ((cg ^ (nl & 7)) * 8));
      }
      #pragma unroll
      for (int i = 0; i < 4; ++i)
        #pragma unroll
        for (int j = 0; j < 4; ++j)
          acc[i][j] = mfma16(af[i], bfr[j], acc[i][j]);
    }
    __syncthreads();
  }
  #pragma unroll
  for (int i = 0; i < 4; ++i)
    #pragma unroll
    for (int j = 0; j < 4; ++j) {
      int col = wc + j * 16 + lm;
      float bv = bias[bcol * 128 + col];
      #pragma unroll
      for (int p = 0; p < 4; ++p)
        Ts[(wr + i * 16 + q * 4 + p) * 136 + col] = __float2half(acc[i][j][p] + bv);
    }
  __syncthreads();
  int rg = tid >> 4, cl = tid & 15;
  #pragma unroll
  for (int v = 0; v < 8; ++v) {
    int row = v * 16 + rg;
    UH t; t.v = *(const short8*)(Ts + row * 136 + cl * 8);
    UB o;
    #pragma unroll
    for (int e = 0; e < 8; ++e) o.e[e] = __float2bfloat16(fmaxf(__half2float(t.e[e]), 0.f));
    *(short8*)(out + (size_t)(brow * 128 + row) * 512 + cout + bcol * 128 + cl * 8) = o.v;
  }
}

// ---- GRU phase 1: zr = h @ Wh_zr, gate, write zh / rhb ---------------------
// grid (64, 4): 64 row-groups x 4 col-slices of 256. One block per CU.
// A (h, 64x512) staged once in LDS (XOR-swizzled); B streamed from L2 in
// fragment-linear layout (1 KB/frag, lane-contiguous) - no LDS staging for B.
__global__ __launch_bounds__(256, 1)
void gruz(const bf16* __restrict__ hsb, const bf16* __restrict__ Wzr,
          const bf16* __restrict__ xz, __half* __restrict__ zh,
          bf16* __restrict__ rhb, int t0)
{
  __shared__ __align__(16) bf16 As[64 * 512];   // 64 KB
  __half* Ts = (__half*)As;                     // [64][264] alias (after GEMM)

  const int tid  = threadIdx.x;
  const int w    = tid >> 6, lane = tid & 63;
  const int lm   = lane & 15, q = lane >> 4;
  const int g    = blockIdx.x, s = blockIdx.y;
  const int grow = g * 64;

  f32x4 acc[4][4];
  #pragma unroll
  for (int mf = 0; mf < 4; ++mf)
    #pragma unroll
    for (int nf = 0; nf < 4; ++nf) acc[mf][nf] = (f32x4){0.f, 0.f, 0.f, 0.f};

  if (!t0) {
    // stage A: wave w stages rows [w*16, w*16+16), src pre-swizzled
    #pragma unroll
    for (int j = 0; j < 16; ++j) {
      int row = w * 16 + j;
      gl_lds16(hsb + (size_t)(grow + row) * 512 + ((lane ^ (row & 7)) * 8),
               As + row * 512);
    }
    __syncthreads();
    const bf16* Bp = Wzr + (size_t)(s * 16 + w * 4) * 8192 + lane * 8;
    #pragma unroll
    for (int KS = 0; KS < 16; ++KS) {
      short8 a[4];
      #pragma unroll
      for (int mf = 0; mf < 4; ++mf) {
        int row = mf * 16 + lm;
        a[mf] = *(const short8*)(As + row * 512 + (((KS * 4 + q) ^ (row & 7)) * 8));
      }
      #pragma unroll
      for (int nf = 0; nf < 4; ++nf) {
        short8 b = *(const short8*)(Bp + (size_t)nf * 8192 + KS * 512);
        #pragma unroll
        for (int mf = 0; mf < 4; ++mf)
          acc[mf][nf] = mfma16(a[mf], b, acc[mf][nf]);
      }
    }
    __syncthreads();   // A dead; Ts may overwrite
  }

  #pragma unroll
  for (int mf = 0; mf < 4; ++mf)
    #pragma unroll
    for (int nf = 0; nf < 4; ++nf)
      #pragma unroll
      for (int p = 0; p < 4; ++p)
        Ts[(mf * 16 + q * 4 + p) * 264 + w * 64 + nf * 16 + lm] =
          __float2half(acc[mf][nf][p]);
  __syncthreads();

  // gate pass: thread -> (row, 64-col span); global zr col = s*256 + c
  const int row = tid >> 2, c0 = (tid & 3) * 64;
  const size_t gr = (size_t)(grow + row);
  #pragma unroll
  for (int j = 0; j < 8; ++j) {
    int c = c0 + j * 8;
    UH tv; tv.v = *(const short8*)(Ts + row * 264 + c);
    UB xv; xv.v = *(const short8*)(xz + gr * 1024 + s * 256 + c);
    if (s < 2) {                                // z gate -> zh (f16)
      UH o;
      #pragma unroll
      for (int e = 0; e < 8; ++e)
        o.e[e] = __float2half(sigf(__half2float(tv.e[e]) + (float)xv.e[e]));
      *(short8*)(zh + gr * 512 + s * 256 + c) = o.v;
    } else {                                    // r gate * h -> rhb (bf16)
      int rcol = (s - 2) * 256 + c;
      UB o;
      if (t0) {
        #pragma unroll
        for (int e = 0; e < 8; ++e) o.e[e] = __float2bfloat16(0.f);
      } else {
        UB h8; h8.v = *(const short8*)(hsb + gr * 512 + rcol);
        #pragma unroll
        for (int e = 0; e < 8; ++e) {
          float r = sigf(__half2float(tv.e[e]) + (float)xv.e[e]);
          o.e[e] = __float2bfloat16(r * (float)h8.e[e]);
        }
      }
      *(short8*)(rhb + gr * 512 + rcol) = o.v;
    }
  }
}

// ---- GRU phase 2: c = (r*h) @ Wh_c, state update in place ------------------
// grid (64, 4): 64 row-groups x 4 col-slices of 128.
__global__ __launch_bounds__(256, 1)
void gruc(const bf16* __restrict__ rhb, const bf16* __restrict__ Wc,
          const bf16* __restrict__ xc, const __half* __restrict__ zh,
          bf16* __restrict__ hsb, int t0)
{
  __shared__ __align__(16) bf16 As[64 * 512];   // 64 KB
  __half* Ts = (__half*)As;                     // [64][136] alias

  const int tid  = threadIdx.x;
  const int w    = tid >> 6, lane = tid & 63;
  const int lm   = lane & 15, q = lane >> 4;
  const int g    = blockIdx.x, s = blockIdx.y;
  const int grow = g * 64;

  f32x4 acc[4][2];
  #pragma unroll
  for (int mf = 0; mf < 4; ++mf)
    #pragma unroll
    for (int nf = 0; nf < 2; ++nf) acc[mf][nf] = (f32x4){0.f, 0.f, 0.f, 0.f};

  if (!t0) {
    #pragma unroll
    for (int j = 0; j < 16; ++j) {
      int row = w * 16 + j;
      gl_lds16(rhb + (size_t)(grow + row) * 512 + ((lane ^ (row & 7)) * 8),
               As + row * 512);
    }
    __syncthreads();
    const bf16* Bp = Wc + (size_t)(s * 8 + w * 2) * 8192 + lane * 8;
    #pragma unroll
    for (int KS = 0; KS < 16; ++KS) {
      short8 a[4];
      #pragma unroll
      for (int mf = 0; mf < 4; ++mf) {
        int row = mf * 16 + lm;
        a[mf] = *(const short8*)(As + row * 512 + (((KS * 4 + q) ^ (row & 7)) * 8));
      }
      #pragma unroll
      for (int nf = 0; nf < 2; ++nf) {
        short8 b = *(const short8*)(Bp + (size_t)nf * 8192 + KS * 512);
        #pragma unroll
        for (int mf = 0; mf < 4; ++mf)
          acc[mf][nf] = mfma16(a[mf], b, acc[mf][nf]);
      }
    }
    __syncthreads();
  }

  #pragma unroll
  for (int mf = 0; mf < 4; ++mf)
    #pragma unroll
    for (int nf = 0; nf < 2; ++nf)
      #pragma unroll
      for (int p = 0; p < 4; ++p)
        Ts[(mf * 16 + q * 4 + p) * 136 + w * 32 + nf * 16 + lm] =
          __float2half(acc[mf][nf][p]);
  __syncthreads();

  // update pass: thread -> (row, 32-col span); global hid col = s*128 + c
  const int row = tid >> 2, c0 = (tid & 3) * 32;
  const size_t gr = (size_t)(grow + row);
  #pragma unroll
  for (int j = 0; j < 4; ++j) {
    int c = c0 + j * 8;
    int hc = s * 128 + c;
    UH tv; tv.v = *(const short8*)(Ts + row * 136 + c);
    UB xv; xv.v = *(const short8*)(xc + gr * 512 + hc);
    UH zv; zv.v = *(const short8*)(zh + gr * 512 + hc);
    UB h8;
    if (!t0) h8.v = *(const short8*)(hsb + gr * 512 + hc);
    UB o;
    #pragma unroll
    for (int e = 0; e < 8; ++e) {
      float cd = tanhf(__half2float(tv.e[e]) + (float)xv.e[e]);
      float zc = __half2float(zv.e[e]);
      float ho = t0 ? 0.f : (float)h8.e[e];
      o.e[e] = __float2bfloat16(zc * ho + (1.f - zc) * cd);
    }
    *(short8*)(hsb + gr * 512 + hc) = o.v;
  }
}

// ---- one-shot weight transpose/convert ----
// Wh_zr / Wh_c packed in MFMA-fragment-linear layout:
//   element (n,k) -> ((n>>4)*16 + (k>>5))*512 + ((k>>3)&3)*128 + (n&15)*8 + (k&7)
__global__ void prep(const float* __restrict__ Wh_zr, const float* __restrict__ Wh_c,
                     const float* __restrict__ Wx_zr, const float* __restrict__ Wx_c,
                     const float* __restrict__ W_gcn,
                     bf16* __restrict__ Whzrt, bf16* __restrict__ Whct,
                     bf16* __restrict__ Wxzrt, bf16* __restrict__ Wxct,
                     bf16* __restrict__ Wgt) {
  int i = blockIdx.x * 256 + threadIdx.x;   // grid 6272
  if (i < 524288) {
    int n = i >> 9, k = i & 511;
    int off = ((n >> 4) * 16 + (k >> 5)) * 512 + ((k >> 3) & 3) * 128 + (n & 15) * 8 + (k & 7);
    Whzrt[off] = __float2bfloat16(Wh_zr[(size_t)k * 1024 + n]);
  } else if (i < 786432) {
    int j = i - 524288; int n = j >> 9, k = j & 511;
    int off = ((n >> 4) * 16 + (k >> 5)) * 512 + ((k >> 3) & 3) * 128 + (n & 15) * 8 + (k & 7);
    Whct[off] = __float2bfloat16(Wh_c[(size_t)k * 512 + n]);
  } else if (i < 1310720) {
    int j = i - 786432; int n = j >> 9, k = j & 511;
    Wxzrt[j] = __float2bfloat16(Wx_zr[(size_t)k * 1024 + n]);
  } else if (i < 1572864) {
    int j = i - 1310720; int n = j >> 9, k = j & 511;
    Wxct[j] = __float2bfloat16(Wx_c[(size_t)k * 512 + n]);
  } else {
    int j = i - 1572864; int n = j >> 7, k = j & 127;
    Wgt[j] = __float2bfloat16(W_gcn[(size_t)k * 256 + n]);
  }
}

// ---- epilogue kernels (green since R13) ----
__global__ void norm_lvec(const bf16* __restrict__ hsb, const float* __restrict__ Wl,
                          const float* __restrict__ bl, const float* __restrict__ hv,
                          bf16* __restrict__ Htrb, float* __restrict__ lv,
                          float* __restrict__ hn) {
  int w = threadIdx.x >> 6, lane = threadIdx.x & 63;
  if (blockIdx.x == 1024) {
    float x[8], ss = 0.f;
    #pragma unroll
    for (int j = 0; j < 8; ++j) { x[j] = hv[w * 512 + lane * 8 + j]; ss += x[j] * x[j]; }
    ss = wred(ss);
    float inv = 1.f / fmaxf(sqrtf(ss), 1e-12f);
    #pragma unroll
    for (int j = 0; j < 8; ++j) hn[w * 512 + lane * 8 + j] = x[j] * inv;
    return;
  }
  int n = blockIdx.x * 4 + w;
  float x[8], ss = 0.f;
  #pragma unroll
  for (int j = 0; j < 8; ++j) {
    x[j] = (float)hsb[(size_t)n * 512 + lane * 8 + j];
    ss += x[j] * x[j];
  }
  ss = wred(ss);
  float inv = 1.f / fmaxf(sqrtf(ss), 1e-12f);
  float dot = 0.f;
  #pragma unroll
  for (int j = 0; j < 8; ++j) {
    float vv = x[j] * inv;
    Htrb[(size_t)n * 512 + lane * 8 + j] = __float2bfloat16(vv);
    dot += vv * Wl[lane * 8 + j];
  }
  dot = wred(dot);
  if (lane == 0) lv[n] = sigf(dot + bl[0]);
}

__global__ void htf(const bf16* __restrict__ Htrb, const float* __restrict__ xf,
                    const float* __restrict__ Wc, const float* __restrict__ bc,
                    const float* __restrict__ lv, float* __restrict__ v) {
  __shared__ float fin_s[4][64];
  int ch = blockIdx.x;                              // grid 64, block 512
  int d = threadIdx.x;
  int n0 = ch * 64;
  if (d < 256) {
    int t = d >> 6, i = d & 63, n = n0 + i;
    float g = bc[t];
    #pragma unroll
    for (int tt = 0; tt < 5; ++tt) g += xf[tt * 4096 + n] * Wc[tt * 4 + t];
    fin_s[t][i] = lv[n] * g;
  }
  __syncthreads();
  float s0 = 0.f, s1 = 0.f, s2 = 0.f, s3 = 0.f;
  for (int i = 0; i < 64; ++i) {
    float hv = (float)Htrb[(size_t)(n0 + i) * 512 + d];
    s0 += hv * fin_s[0][i];
    s1 += hv * fin_s[1][i];
    s2 += hv * fin_s[2][i];
    s3 += hv * fin_s[3][i];
  }
  atomicAdd(&v[d], s0);
  atomicAdd(&v[512 + d], s1);
  atomicAdd(&v[1024 + d], s2);
  atomicAdd(&v[1536 + d], s3);
}

__global__ void attk(const bf16* __restrict__ Htrb, const float* __restrict__ v,
                     float* __restrict__ out) {
  int w = threadIdx.x >> 6, lane = threadIdx.x & 63;
  int n = blockIdx.x * 4 + w;
  float x[8];
  #pragma unroll
  for (int j = 0; j < 8; ++j) x[j] = (float)Htrb[(size_t)n * 512 + lane * 8 + j];
  #pragma unroll
  for (int t = 0; t < 4; ++t) {
    float s = 0.f;
    #pragma unroll
    for (int j = 0; j < 8; ++j) s += x[j] * v[t * 512 + lane * 8 + j];
    s = wred(s);
    if (lane == 0) out[t * 4096 + n] = s;
  }
}

__global__ void loff(const bf16* __restrict__ Htrb, const float* __restrict__ hn,
                     const int* __restrict__ ty, float* __restrict__ loffp) {
  int w = threadIdx.x >> 6, lane = threadIdx.x & 63;
  int t = blockIdx.y;
  int m = blockIdx.x * 4 + w;
  const int* row = ty + ((size_t)t * 2048 + m) * 18;
  int pi = row[1];
  float p[8], hv[8], c = 0.f;
  #pragma unroll
  for (int j = 0; j < 8; ++j) {
    p[j]  = (float)Htrb[(size_t)pi * 512 + lane * 8 + j];
    hv[j] = hn[t * 512 + lane * 8 + j];
    c += p[j] * hv[j];
  }
  c = wred(c);
  float a[8], sp = 0.f;
  #pragma unroll
  for (int j = 0; j < 8; ++j) { a[j] = p[j] - 2.f * c * hv[j]; sp += a[j] * p[j]; }
  sp = wred(sp);
  float acc = 0.f;
  for (int k = 0; k < 16; ++k) {
    int ni = row[2 + k];
    float sn = 0.f;
    #pragma unroll
    for (int j = 0; j < 8; ++j) sn += a[j] * (float)Htrb[(size_t)ni * 512 + lane * 8 + j];
    sn = wred(sn);
    acc += fmaxf(sn - sp + 0.5f, 0.f);
  }
  __shared__ float sbuf[4];
  if (lane == 0) sbuf[w] = acc;
  __syncthreads();
  if (threadIdx.x == 0)
    loffp[t * 512 + blockIdx.x] = sbuf[0] + sbuf[1] + sbuf[2] + sbuf[3];
}

__global__ void fini(const float* __restrict__ loffp, const float* __restrict__ lv,
                     const float* __restrict__ yl, float* __restrict__ out) {
  int tid = threadIdx.x, w = tid >> 6, lane = tid & 63;
  float s = 0.f, s2 = 0.f;
  for (int i = tid; i < 2048; i += 256) s += loffp[i];
  for (int i = tid; i < 4096; i += 256) {
    float l = lv[i];
    float ym = 0.25f * (yl[i] + yl[4096 + i] + yl[8192 + i] + yl[12288 + i]);
    s2 += fmaxf(l, 0.f) - l * ym + log1pf(expf(-fabsf(l)));
  }
  s = wred(s); s2 = wred(s2);
  __shared__ float sb[4], sb2[4];
  if (lane == 0) { sb[w] = s; sb2[w] = s2; }
  __syncthreads();
  if (tid == 0) {
    out[16384] = (sb[0] + sb[1] + sb[2] + sb[3]) / (4.f * 2048.f * 16.f);
    out[16385] = (sb2[0] + sb2[1] + sb2[2] + sb2[3]) / 4096.f;
  }
}

__global__ void wsprobe(float marker, float* out) {
  if (threadIdx.x == 0) out[0] = marker;
}

// ---------------- launch ----------------
extern "C" void kernel_launch(void* const* d_in, const int* in_sizes, int n_in,
                              void* d_out, int out_size, void* d_ws, size_t ws_size,
                              hipStream_t stream) {
  const float* x_feature   = (const float*)d_in[0];
  const float* x_graph     = (const float*)d_in[1];
  const float* x_graph_inv = (const float*)d_in[2];
  const int*   temp_y      = (const int*)d_in[3];
  const float* is_leaf     = (const float*)d_in[4];
  const float* W_gcn       = (const float*)d_in[5];
  const float* b_gcn       = (const float*)d_in[6];
  const float* Wx_zr       = (const float*)d_in[7];
  const float* Wh_zr       = (const float*)d_in[8];
  const float* b_zr        = (const float*)d_in[9];
  const float* Wx_c        = (const float*)d_in[10];
  const float* Wh_c        = (const float*)d_in[11];
  const float* b_c         = (const float*)d_in[12];
  const float* h_vecs      = (const float*)d_in[13];
  const float* W_leaf      = (const float*)d_in[14];
  const float* b_leaf      = (const float*)d_in[15];
  const float* W_conv      = (const float*)d_in[16];
  const float* b_conv      = (const float*)d_in[17];
  float* out = (float*)d_out;
  (void)in_sizes; (void)n_in; (void)out_size;

  const size_t NEED = 156000000;
  if (ws_size < NEED) {
    wsprobe<<<1, 64, 0, stream>>>(1000.f + (float)(ws_size >> 20), out);
    return;
  }

  char* ws = (char*)d_ws;
  size_t off = 0;
  auto alloc = [&](size_t bytes) -> void* {
    void* p = ws + off;
    off = (off + bytes + 255) & ~(size_t)255;
    return p;
  };
  bf16*   Whzrt = (bf16*)  alloc((size_t)1024 * 512 * 2);
  bf16*   Whct  = (bf16*)  alloc((size_t)512 * 512 * 2);
  bf16*   Wxzrt = (bf16*)  alloc((size_t)1024 * 512 * 2);
  bf16*   Wxct  = (bf16*)  alloc((size_t)512 * 512 * 2);
  bf16*   Wgt   = (bf16*)  alloc((size_t)256 * 128 * 2);
  bf16*   hfin  = (bf16*)  alloc((size_t)32768 * 512 * 2);  // 32 MB
  bf16*   xzrp  = (bf16*)  alloc((size_t)32768 * 1024 * 2); // 64 MB (bias folded)
  bf16*   xcp   = (bf16*)  alloc((size_t)32768 * 512 * 2);  // 32 MB (bias folded)
  bf16*   hsb   = (bf16*)  alloc((size_t)4096 * 512 * 2);
  bf16*   rhb   = (bf16*)  alloc((size_t)4096 * 512 * 2);
  __half* zh    = (__half*)alloc((size_t)4096 * 512 * 2);
  float*  lv    = (float*) alloc(4096 * 4);
  float*  hn    = (float*) alloc(4 * 512 * 4);
  float*  v     = (float*) alloc(4 * 512 * 4);
  float*  loffp = (float*) alloc(2048 * 4);
  bf16*   Htrb  = hfin;   // overlay: hfin dead after gemmx consumes it

  hipMemsetAsync(v, 0, 4 * 512 * 4, stream);

  prep<<<6272, 256, 0, stream>>>(Wh_zr, Wh_c, Wx_zr, Wx_c, W_gcn,
                                 Whzrt, Whct, Wxzrt, Wxct, Wgt);
  gcnk<<<dim3(256, 2, 2), 256, 0, stream>>>(x_graph, x_graph_inv, Wgt, b_gcn, hfin);
  gemmx<<<dim3(256, 12), 256, 0, stream>>>(hfin, Wxzrt, Wxct, b_zr, b_c, xzrp, xcp);

  // sequential GRU: full-machine per phase (256 blocks), B from L2
  for (int t = 0; t < 8; ++t) {
    gruz<<<dim3(64, 4), 256, 0, stream>>>(hsb, Whzrt,
                                          xzrp + (size_t)t * 4096 * 1024,
                                          zh, rhb, t == 0);
    gruc<<<dim3(64, 4), 256, 0, stream>>>(rhb, Whct,
                                          xcp + (size_t)t * 4096 * 512,
                                          zh, hsb, t == 0);
  }

  norm_lvec<<<1025, 256, 0, stream>>>(hsb, W_leaf, b_leaf, h_vecs, Htrb, lv, hn);
  htf<<<64, 512, 0, stream>>>(Htrb, x_feature, W_conv, b_conv, lv, v);
  attk<<<1024, 256, 0, stream>>>(Htrb, v, out);
  loff<<<dim3(512, 4), 256, 0, stream>>>(Htrb, hn, temp_y, loffp);
  fini<<<1, 256, 0, stream>>>(loffp, lv, is_leaf, out);
}

// Round 3
// 423.785 us; speedup vs baseline: 1.6210x; 1.2286x over previous
//
#include <hip/hip_runtime.h>
#include <hip/hip_bf16.h>
#include <hip/hip_fp16.h>
#include <math.h>

typedef __hip_bfloat16 bf16;
typedef __attribute__((ext_vector_type(8))) short short8;   // 8 bf16 / 8 f16 (16 B)
typedef __attribute__((ext_vector_type(4))) float f32x4;    // MFMA C/D frag

union UB { short8 v; bf16 e[8]; };
union UH { short8 v; __half e[8]; };

// ---------------- helpers ----------------
__device__ __forceinline__ float wred(float v) {
  #pragma unroll
  for (int o = 32; o > 0; o >>= 1) v += __shfl_xor(v, o, 64);
  return v;
}
__device__ __forceinline__ float sigf(float x) { return 1.f / (1.f + expf(-x)); }

__device__ __forceinline__ void gl_lds16(const bf16* g, const bf16* lds) {
  __builtin_amdgcn_global_load_lds((const __attribute__((address_space(1))) void*)g,
                                   (__attribute__((address_space(3))) void*)lds,
                                   16, 0, 0);
}
__device__ __forceinline__ f32x4 mfma16(short8 a, short8 b, f32x4 c) {
  return __builtin_amdgcn_mfma_f32_16x16x32_bf16(a, b, c, 0, 0, 0);
}

// ---- merged batch GEMM: xzrp + xcp, K=512, line-coalesced epilogue ----
__global__ __launch_bounds__(256, 2)
void gemmx(const bf16* __restrict__ A, const bf16* __restrict__ Wxzrt,
           const bf16* __restrict__ Wxct, const float* __restrict__ b_zr,
           const float* __restrict__ b_c, bf16* __restrict__ xzrp,
           bf16* __restrict__ xcp)
{
  __shared__ __align__(16) char smem[34816];
  bf16* As = (bf16*)smem;
  bf16* Bs = (bf16*)(smem + 16384);
  __half* Ts = (__half*)smem;

  const int tid  = threadIdx.x;
  const int wave = tid >> 6, lane = tid & 63;
  const int lm = lane & 15, q = lane >> 4;
  const int brow = blockIdx.x, bcol = blockIdx.y;
  const int wr = (wave >> 1) * 64, wc = (wave & 1) * 64;
  const int srow = lane >> 3, sslot = lane & 7;

  const bf16* Bt; const float* bias; bf16* C; int ldc, colbase;
  if (bcol < 8) { Bt = Wxzrt + (size_t)bcol * 128 * 512; bias = b_zr; C = xzrp; ldc = 1024; colbase = bcol * 128; }
  else          { Bt = Wxct + (size_t)(bcol - 8) * 128 * 512; bias = b_c; C = xcp; ldc = 512; colbase = (bcol - 8) * 128; }

  f32x4 acc[4][4];
  #pragma unroll
  for (int i = 0; i < 4; ++i)
    #pragma unroll
    for (int j = 0; j < 4; ++j) acc[i][j] = (f32x4){0.f, 0.f, 0.f, 0.f};

  for (int kb = 0; kb < 512; kb += 64) {
    #pragma unroll
    for (int j = 0; j < 4; ++j) {
      int ml = wave * 32 + j * 8 + srow;
      int cg = sslot ^ (ml & 7);
      gl_lds16(A + (size_t)(brow * 128 + ml) * 512 + kb + cg * 8, As + (wave * 4 + j) * 512);
      gl_lds16(Bt + (size_t)ml * 512 + kb + cg * 8, Bs + (wave * 4 + j) * 512);
    }
    __syncthreads();
    #pragma unroll
    for (int ks = 0; ks < 2; ++ks) {
      short8 af[4], bfr[4];
      #pragma unroll
      for (int i = 0; i < 4; ++i) {
        int cg = ks * 4 + q;
        int ml = wr + i * 16 + lm;
        af[i]  = *(const short8*)(As + ml * 64 + ((cg ^ (ml & 7)) * 8));
        int nl = wc + i * 16 + lm;
        bfr[i] = *(const short8*)(Bs + nl * 64 + ((cg ^ (nl & 7)) * 8));
      }
      #pragma unroll
      for (int i = 0; i < 4; ++i)
        #pragma unroll
        for (int j = 0; j < 4; ++j)
          acc[i][j] = mfma16(af[i], bfr[j], acc[i][j]);
    }
    __syncthreads();
  }
  #pragma unroll
  for (int i = 0; i < 4; ++i)
    #pragma unroll
    for (int j = 0; j < 4; ++j) {
      int col = wc + j * 16 + lm;
      float bv = bias[colbase + col];
      #pragma unroll
      for (int p = 0; p < 4; ++p)
        Ts[(wr + i * 16 + q * 4 + p) * 136 + col] = __float2half(acc[i][j][p] + bv);
    }
  __syncthreads();
  int rg = tid >> 4, cl = tid & 15;
  #pragma unroll
  for (int v = 0; v < 8; ++v) {
    int row = v * 16 + rg;
    UH t; t.v = *(const short8*)(Ts + row * 136 + cl * 8);
    UB o;
    #pragma unroll
    for (int e = 0; e < 8; ++e) o.e[e] = __float2bfloat16(__half2float(t.e[e]));
    *(short8*)(C + (size_t)(brow * 128 + row) * ldc + colbase + cl * 8) = o.v;
  }
}

// ---- GCN batch GEMM: grid (256, 2, 2), line-coalesced epilogue ----
__global__ __launch_bounds__(256, 2)
void gcnk(const float* __restrict__ Ag, const float* __restrict__ Agi,
          const bf16* __restrict__ Wgt, const float* __restrict__ bias,
          bf16* __restrict__ out)
{
  __shared__ __align__(16) char smem[34816];
  bf16* As = (bf16*)smem;
  bf16* Bs = (bf16*)(smem + 16384);
  __half* Ts = (__half*)smem;

  const int tid  = threadIdx.x;
  const int wave = tid >> 6, lane = tid & 63;
  const int lm = lane & 15, q = lane >> 4;
  const int brow = blockIdx.x, bcol = blockIdx.y;
  const int z = blockIdx.z, cout = z * 256;
  const float* A = z ? Agi : Ag;
  const int wr = (wave >> 1) * 64, wc = (wave & 1) * 64;
  const int srow = lane >> 3, sslot = lane & 7;

  f32x4 acc[4][4];
  #pragma unroll
  for (int i = 0; i < 4; ++i)
    #pragma unroll
    for (int j = 0; j < 4; ++j) acc[i][j] = (f32x4){0.f, 0.f, 0.f, 0.f};

  for (int kb = 0; kb < 128; kb += 64) {
    #pragma unroll
    for (int j = 0; j < 4; ++j) {
      int ml = wave * 32 + j * 8 + srow;
      int cg = sslot ^ (ml & 7);
      const float* src = A + (size_t)(brow * 128 + ml) * 128 + kb + cg * 8;
      bf16 tmp[8];
      #pragma unroll
      for (int e = 0; e < 8; ++e) tmp[e] = __float2bfloat16(src[e]);
      *(short8*)(As + ml * 64 + sslot * 8) = *(const short8*)tmp;
      gl_lds16(Wgt + (size_t)(bcol * 128 + ml) * 128 + kb + cg * 8,
               Bs + (wave * 4 + j) * 512);
    }
    __syncthreads();
    #pragma unroll
    for (int ks = 0; ks < 2; ++ks) {
      short8 af[4], bfr[4];
      #pragma unroll
      for (int i = 0; i < 4; ++i) {
        int cg = ks * 4 + q;
        int ml = wr + i * 16 + lm;
        af[i]  = *(const short8*)(As + ml * 64 + ((cg ^ (ml & 7)) * 8));
        int nl = wc + i * 16 + lm;
        bfr[i] = *(const short8*)(Bs + nl * 64 + ((cg ^ (nl & 7)) * 8));
      }
      #pragma unroll
      for (int i = 0; i < 4; ++i)
        #pragma unroll
        for (int j = 0; j < 4; ++j)
          acc[i][j] = mfma16(af[i], bfr[j], acc[i][j]);
    }
    __syncthreads();
  }
  #pragma unroll
  for (int i = 0; i < 4; ++i)
    #pragma unroll
    for (int j = 0; j < 4; ++j) {
      int col = wc + j * 16 + lm;
      float bv = bias[bcol * 128 + col];
      #pragma unroll
      for (int p = 0; p < 4; ++p)
        Ts[(wr + i * 16 + q * 4 + p) * 136 + col] = __float2half(acc[i][j][p] + bv);
    }
  __syncthreads();
  int rg = tid >> 4, cl = tid & 15;
  #pragma unroll
  for (int v = 0; v < 8; ++v) {
    int row = v * 16 + rg;
    UH t; t.v = *(const short8*)(Ts + row * 136 + cl * 8);
    UB o;
    #pragma unroll
    for (int e = 0; e < 8; ++e) o.e[e] = __float2bfloat16(fmaxf(__half2float(t.e[e]), 0.f));
    *(short8*)(out + (size_t)(brow * 128 + row) * 512 + cout + bcol * 128 + cl * 8) = o.v;
  }
}

// ---- GRU phase 1: zr = h @ Wh_zr, gate, write zh / rhb ---------------------
// grid (64, 4), 512 thr: block = 64 rows x 256 cols; 8 waves/block = 2/SIMD.
// A staged once in LDS (XOR-swizzled); B streamed from L2 (fragment-linear),
// depth-2 register prefetch. Gate operands prefetched before GEMM.
__global__ __launch_bounds__(512, 2)
void gruz(const bf16* __restrict__ hsb, const bf16* __restrict__ Wzr,
          const bf16* __restrict__ xz, __half* __restrict__ zh,
          bf16* __restrict__ rhb, int t0)
{
  __shared__ __align__(16) bf16 As[64 * 512];   // 64 KB
  __half* Ts = (__half*)As;                     // [64][264] alias

  const int tid  = threadIdx.x;
  const int w    = tid >> 6, lane = tid & 63;
  const int lm   = lane & 15, q = lane >> 4;
  const int g    = blockIdx.x, s = blockIdx.y;
  const int grow = g * 64;

  // epilogue coords + early global prefetch (latency hides under GEMM)
  const int prow = tid >> 3, pc0 = (tid & 7) * 32;
  const size_t gr = (size_t)(grow + prow);
  UB xv[4], h8[4];
  #pragma unroll
  for (int j = 0; j < 4; ++j)
    xv[j].v = *(const short8*)(xz + gr * 1024 + s * 256 + pc0 + j * 8);
  if (s >= 2 && !t0) {
    #pragma unroll
    for (int j = 0; j < 4; ++j)
      h8[j].v = *(const short8*)(hsb + gr * 512 + (s - 2) * 256 + pc0 + j * 8);
  }

  f32x4 acc[4][2];
  #pragma unroll
  for (int mf = 0; mf < 4; ++mf)
    #pragma unroll
    for (int nf = 0; nf < 2; ++nf) acc[mf][nf] = (f32x4){0.f, 0.f, 0.f, 0.f};

  if (!t0) {
    // stage A: wave w stages rows [w*8, w*8+8), src pre-swizzled
    #pragma unroll
    for (int j = 0; j < 8; ++j) {
      int row = w * 8 + j;
      gl_lds16(hsb + (size_t)(grow + row) * 512 + ((lane ^ (row & 7)) * 8),
               As + row * 512);
    }
    __syncthreads();

    const bf16* Bp = Wzr + (size_t)(s * 16 + w * 2) * 8192 + lane * 8;
    short8 b0[2], b1[2], a[4];
    #pragma unroll
    for (int nf = 0; nf < 2; ++nf) {
      b0[nf] = *(const short8*)(Bp + (size_t)nf * 8192);
      b1[nf] = *(const short8*)(Bp + (size_t)nf * 8192 + 512);
    }
    #pragma unroll
    for (int mf = 0; mf < 4; ++mf) {
      int row = mf * 16 + lm;
      a[mf] = *(const short8*)(As + row * 512 + ((q ^ (row & 7)) * 8));
    }
    #pragma unroll
    for (int KS = 0; KS < 16; ++KS) {
      short8 bn[2], an[4];
      if (KS < 14) {
        #pragma unroll
        for (int nf = 0; nf < 2; ++nf)
          bn[nf] = *(const short8*)(Bp + (size_t)nf * 8192 + (KS + 2) * 512);
      }
      if (KS < 15) {
        #pragma unroll
        for (int mf = 0; mf < 4; ++mf) {
          int row = mf * 16 + lm;
          an[mf] = *(const short8*)(As + row * 512 + ((((KS + 1) * 4 + q) ^ (row & 7)) * 8));
        }
      }
      #pragma unroll
      for (int nf = 0; nf < 2; ++nf)
        #pragma unroll
        for (int mf = 0; mf < 4; ++mf)
          acc[mf][nf] = mfma16(a[mf], b0[nf], acc[mf][nf]);
      #pragma unroll
      for (int nf = 0; nf < 2; ++nf) { b0[nf] = b1[nf]; b1[nf] = bn[nf]; }
      #pragma unroll
      for (int mf = 0; mf < 4; ++mf) a[mf] = an[mf];
    }
    __syncthreads();   // A dead; Ts may overwrite
  }

  #pragma unroll
  for (int mf = 0; mf < 4; ++mf)
    #pragma unroll
    for (int nf = 0; nf < 2; ++nf)
      #pragma unroll
      for (int p = 0; p < 4; ++p)
        Ts[(mf * 16 + q * 4 + p) * 264 + w * 32 + nf * 16 + lm] =
          __float2half(acc[mf][nf][p]);
  __syncthreads();

  // gate pass: thread -> (row, 32-col span); global zr col = s*256 + c
  #pragma unroll
  for (int j = 0; j < 4; ++j) {
    int c = pc0 + j * 8;
    UH tv; tv.v = *(const short8*)(Ts + prow * 264 + c);
    if (s < 2) {                                // z gate -> zh (f16)
      UH o;
      #pragma unroll
      for (int e = 0; e < 8; ++e)
        o.e[e] = __float2half(sigf(__half2float(tv.e[e]) + (float)xv[j].e[e]));
      *(short8*)(zh + gr * 512 + s * 256 + c) = o.v;
    } else if (!t0) {                           // r gate * h -> rhb (bf16)
      UB o;
      #pragma unroll
      for (int e = 0; e < 8; ++e) {
        float r = sigf(__half2float(tv.e[e]) + (float)xv[j].e[e]);
        o.e[e] = __float2bfloat16(r * (float)h8[j].e[e]);
      }
      *(short8*)(rhb + gr * 512 + (s - 2) * 256 + c) = o.v;
    }
    // t0 && s>=2: rhb not read by gruc at t0 -> skip store
  }
}

// ---- GRU phase 2: c = (r*h) @ Wh_c, state update in place ------------------
// grid (64, 4), 512 thr: block = 64 rows x 128 cols; waves tiled 2x4.
__global__ __launch_bounds__(512, 2)
void gruc(const bf16* __restrict__ rhb, const bf16* __restrict__ Wc,
          const bf16* __restrict__ xc, const __half* __restrict__ zh,
          bf16* __restrict__ hsb, int t0)
{
  __shared__ __align__(16) bf16 As[64 * 512];   // 64 KB
  __half* Ts = (__half*)As;                     // [64][136] alias

  const int tid  = threadIdx.x;
  const int w    = tid >> 6, lane = tid & 63;
  const int lm   = lane & 15, q = lane >> 4;
  const int rh_  = w & 1, cq = w >> 1;          // wave tile: 2 row-halves x 4 col-quads
  const int g    = blockIdx.x, s = blockIdx.y;
  const int grow = g * 64;

  const int prow = tid >> 3, pc0 = (tid & 7) * 16;
  const size_t gr = (size_t)(grow + prow);
  UB xv[2], h8[2]; UH zv[2];
  #pragma unroll
  for (int j = 0; j < 2; ++j) {
    int hc = s * 128 + pc0 + j * 8;
    xv[j].v = *(const short8*)(xc + gr * 512 + hc);
    zv[j].v = *(const short8*)(zh + gr * 512 + hc);
  }
  if (!t0) {
    #pragma unroll
    for (int j = 0; j < 2; ++j)
      h8[j].v = *(const short8*)(hsb + gr * 512 + s * 128 + pc0 + j * 8);
  }

  f32x4 acc[2][2];
  #pragma unroll
  for (int mf = 0; mf < 2; ++mf)
    #pragma unroll
    for (int nf = 0; nf < 2; ++nf) acc[mf][nf] = (f32x4){0.f, 0.f, 0.f, 0.f};

  if (!t0) {
    #pragma unroll
    for (int j = 0; j < 8; ++j) {
      int row = w * 8 + j;
      gl_lds16(rhb + (size_t)(grow + row) * 512 + ((lane ^ (row & 7)) * 8),
               As + row * 512);
    }
    __syncthreads();

    const bf16* Bp = Wc + (size_t)(s * 8 + cq * 2) * 8192 + lane * 8;
    short8 b0[2], b1[2], a[2];
    #pragma unroll
    for (int nf = 0; nf < 2; ++nf) {
      b0[nf] = *(const short8*)(Bp + (size_t)nf * 8192);
      b1[nf] = *(const short8*)(Bp + (size_t)nf * 8192 + 512);
    }
    #pragma unroll
    for (int mf = 0; mf < 2; ++mf) {
      int row = rh_ * 32 + mf * 16 + lm;
      a[mf] = *(const short8*)(As + row * 512 + ((q ^ (row & 7)) * 8));
    }
    #pragma unroll
    for (int KS = 0; KS < 16; ++KS) {
      short8 bn[2], an[2];
      if (KS < 14) {
        #pragma unroll
        for (int nf = 0; nf < 2; ++nf)
          bn[nf] = *(const short8*)(Bp + (size_t)nf * 8192 + (KS + 2) * 512);
      }
      if (KS < 15) {
        #pragma unroll
        for (int mf = 0; mf < 2; ++mf) {
          int row = rh_ * 32 + mf * 16 + lm;
          an[mf] = *(const short8*)(As + row * 512 + ((((KS + 1) * 4 + q) ^ (row & 7)) * 8));
        }
      }
      #pragma unroll
      for (int nf = 0; nf < 2; ++nf)
        #pragma unroll
        for (int mf = 0; mf < 2; ++mf)
          acc[mf][nf] = mfma16(a[mf], b0[nf], acc[mf][nf]);
      #pragma unroll
      for (int nf = 0; nf < 2; ++nf) { b0[nf] = b1[nf]; b1[nf] = bn[nf]; }
      #pragma unroll
      for (int mf = 0; mf < 2; ++mf) a[mf] = an[mf];
    }
    __syncthreads();
  }

  #pragma unroll
  for (int mf = 0; mf < 2; ++mf)
    #pragma unroll
    for (int nf = 0; nf < 2; ++nf)
      #pragma unroll
      for (int p = 0; p < 4; ++p)
        Ts[(rh_ * 32 + mf * 16 + q * 4 + p) * 136 + cq * 32 + nf * 16 + lm] =
          __float2half(acc[mf][nf][p]);
  __syncthreads();

  // update pass: thread -> (row, 16-col span); global hid col = s*128 + c
  #pragma unroll
  for (int j = 0; j < 2; ++j) {
    int c = pc0 + j * 8;
    int hc = s * 128 + c;
    UH tv; tv.v = *(const short8*)(Ts + prow * 136 + c);
    UB o;
    #pragma unroll
    for (int e = 0; e < 8; ++e) {
      float cd = tanhf(__half2float(tv.e[e]) + (float)xv[j].e[e]);
      float zc = __half2float(zv[j].e[e]);
      float ho = t0 ? 0.f : (float)h8[j].e[e];
      o.e[e] = __float2bfloat16(zc * ho + (1.f - zc) * cd);
    }
    *(short8*)(hsb + gr * 512 + hc) = o.v;
  }
}

// ---- one-shot weight transpose/convert ----
// Wh_zr / Wh_c packed in MFMA-fragment-linear layout:
//   element (n,k) -> ((n>>4)*16 + (k>>5))*512 + ((k>>3)&3)*128 + (n&15)*8 + (k&7)
__global__ void prep(const float* __restrict__ Wh_zr, const float* __restrict__ Wh_c,
                     const float* __restrict__ Wx_zr, const float* __restrict__ Wx_c,
                     const float* __restrict__ W_gcn,
                     bf16* __restrict__ Whzrt, bf16* __restrict__ Whct,
                     bf16* __restrict__ Wxzrt, bf16* __restrict__ Wxct,
                     bf16* __restrict__ Wgt) {
  int i = blockIdx.x * 256 + threadIdx.x;   // grid 6272
  if (i < 524288) {
    int n = i >> 9, k = i & 511;
    int off = ((n >> 4) * 16 + (k >> 5)) * 512 + ((k >> 3) & 3) * 128 + (n & 15) * 8 + (k & 7);
    Whzrt[off] = __float2bfloat16(Wh_zr[(size_t)k * 1024 + n]);
  } else if (i < 786432) {
    int j = i - 524288; int n = j >> 9, k = j & 511;
    int off = ((n >> 4) * 16 + (k >> 5)) * 512 + ((k >> 3) & 3) * 128 + (n & 15) * 8 + (k & 7);
    Whct[off] = __float2bfloat16(Wh_c[(size_t)k * 512 + n]);
  } else if (i < 1310720) {
    int j = i - 786432; int n = j >> 9, k = j & 511;
    Wxzrt[j] = __float2bfloat16(Wx_zr[(size_t)k * 1024 + n]);
  } else if (i < 1572864) {
    int j = i - 1310720; int n = j >> 9, k = j & 511;
    Wxct[j] = __float2bfloat16(Wx_c[(size_t)k * 512 + n]);
  } else {
    int j = i - 1572864; int n = j >> 7, k = j & 127;
    Wgt[j] = __float2bfloat16(W_gcn[(size_t)k * 256 + n]);
  }
}

// ---- epilogue kernels (green since R13) ----
__global__ void norm_lvec(const bf16* __restrict__ hsb, const float* __restrict__ Wl,
                          const float* __restrict__ bl, const float* __restrict__ hv,
                          bf16* __restrict__ Htrb, float* __restrict__ lv,
                          float* __restrict__ hn) {
  int w = threadIdx.x >> 6, lane = threadIdx.x & 63;
  if (blockIdx.x == 1024) {
    float x[8], ss = 0.f;
    #pragma unroll
    for (int j = 0; j < 8; ++j) { x[j] = hv[w * 512 + lane * 8 + j]; ss += x[j] * x[j]; }
    ss = wred(ss);
    float inv = 1.f / fmaxf(sqrtf(ss), 1e-12f);
    #pragma unroll
    for (int j = 0; j < 8; ++j) hn[w * 512 + lane * 8 + j] = x[j] * inv;
    return;
  }
  int n = blockIdx.x * 4 + w;
  float x[8], ss = 0.f;
  #pragma unroll
  for (int j = 0; j < 8; ++j) {
    x[j] = (float)hsb[(size_t)n * 512 + lane * 8 + j];
    ss += x[j] * x[j];
  }
  ss = wred(ss);
  float inv = 1.f / fmaxf(sqrtf(ss), 1e-12f);
  float dot = 0.f;
  #pragma unroll
  for (int j = 0; j < 8; ++j) {
    float vv = x[j] * inv;
    Htrb[(size_t)n * 512 + lane * 8 + j] = __float2bfloat16(vv);
    dot += vv * Wl[lane * 8 + j];
  }
  dot = wred(dot);
  if (lane == 0) lv[n] = sigf(dot + bl[0]);
}

__global__ void htf(const bf16* __restrict__ Htrb, const float* __restrict__ xf,
                    const float* __restrict__ Wc, const float* __restrict__ bc,
                    const float* __restrict__ lv, float* __restrict__ v) {
  __shared__ float fin_s[4][64];
  int ch = blockIdx.x;                              // grid 64, block 512
  int d = threadIdx.x;
  int n0 = ch * 64;
  if (d < 256) {
    int t = d >> 6, i = d & 63, n = n0 + i;
    float g = bc[t];
    #pragma unroll
    for (int tt = 0; tt < 5; ++tt) g += xf[tt * 4096 + n] * Wc[tt * 4 + t];
    fin_s[t][i] = lv[n] * g;
  }
  __syncthreads();
  float s0 = 0.f, s1 = 0.f, s2 = 0.f, s3 = 0.f;
  for (int i = 0; i < 64; ++i) {
    float hv = (float)Htrb[(size_t)(n0 + i) * 512 + d];
    s0 += hv * fin_s[0][i];
    s1 += hv * fin_s[1][i];
    s2 += hv * fin_s[2][i];
    s3 += hv * fin_s[3][i];
  }
  atomicAdd(&v[d], s0);
  atomicAdd(&v[512 + d], s1);
  atomicAdd(&v[1024 + d], s2);
  atomicAdd(&v[1536 + d], s3);
}

__global__ void attk(const bf16* __restrict__ Htrb, const float* __restrict__ v,
                     float* __restrict__ out) {
  int w = threadIdx.x >> 6, lane = threadIdx.x & 63;
  int n = blockIdx.x * 4 + w;
  float x[8];
  #pragma unroll
  for (int j = 0; j < 8; ++j) x[j] = (float)Htrb[(size_t)n * 512 + lane * 8 + j];
  #pragma unroll
  for (int t = 0; t < 4; ++t) {
    float s = 0.f;
    #pragma unroll
    for (int j = 0; j < 8; ++j) s += x[j] * v[t * 512 + lane * 8 + j];
    s = wred(s);
    if (lane == 0) out[t * 4096 + n] = s;
  }
}

__global__ void loff(const bf16* __restrict__ Htrb, const float* __restrict__ hn,
                     const int* __restrict__ ty, float* __restrict__ loffp) {
  int w = threadIdx.x >> 6, lane = threadIdx.x & 63;
  int t = blockIdx.y;
  int m = blockIdx.x * 4 + w;
  const int* row = ty + ((size_t)t * 2048 + m) * 18;
  int pi = row[1];
  float p[8], hv[8], c = 0.f;
  #pragma unroll
  for (int j = 0; j < 8; ++j) {
    p[j]  = (float)Htrb[(size_t)pi * 512 + lane * 8 + j];
    hv[j] = hn[t * 512 + lane * 8 + j];
    c += p[j] * hv[j];
  }
  c = wred(c);
  float a[8], sp = 0.f;
  #pragma unroll
  for (int j = 0; j < 8; ++j) { a[j] = p[j] - 2.f * c * hv[j]; sp += a[j] * p[j]; }
  sp = wred(sp);
  float acc = 0.f;
  for (int k = 0; k < 16; ++k) {
    int ni = row[2 + k];
    float sn = 0.f;
    #pragma unroll
    for (int j = 0; j < 8; ++j) sn += a[j] * (float)Htrb[(size_t)ni * 512 + lane * 8 + j];
    sn = wred(sn);
    acc += fmaxf(sn - sp + 0.5f, 0.f);
  }
  __shared__ float sbuf[4];
  if (lane == 0) sbuf[w] = acc;
  __syncthreads();
  if (threadIdx.x == 0)
    loffp[t * 512 + blockIdx.x] = sbuf[0] + sbuf[1] + sbuf[2] + sbuf[3];
}

__global__ void fini(const float* __restrict__ loffp, const float* __restrict__ lv,
                     const float* __restrict__ yl, float* __restrict__ out) {
  int tid = threadIdx.x, w = tid >> 6, lane = tid & 63;
  float s = 0.f, s2 = 0.f;
  for (int i = tid; i < 2048; i += 256) s += loffp[i];
  for (int i = tid; i < 4096; i += 256) {
    float l = lv[i];
    float ym = 0.25f * (yl[i] + yl[4096 + i] + yl[8192 + i] + yl[12288 + i]);
    s2 += fmaxf(l, 0.f) - l * ym + log1pf(expf(-fabsf(l)));
  }
  s = wred(s); s2 = wred(s2);
  __shared__ float sb[4], sb2[4];
  if (lane == 0) { sb[w] = s; sb2[w] = s2; }
  __syncthreads();
  if (tid == 0) {
    out[16384] = (sb[0] + sb[1] + sb[2] + sb[3]) / (4.f * 2048.f * 16.f);
    out[16385] = (sb2[0] + sb2[1] + sb2[2] + sb2[3]) / 4096.f;
  }
}

__global__ void wsprobe(float marker, float* out) {
  if (threadIdx.x == 0) out[0] = marker;
}

// ---------------- launch ----------------
extern "C" void kernel_launch(void* const* d_in, const int* in_sizes, int n_in,
                              void* d_out, int out_size, void* d_ws, size_t ws_size,
                              hipStream_t stream) {
  const float* x_feature   = (const float*)d_in[0];
  const float* x_graph     = (const float*)d_in[1];
  const float* x_graph_inv = (const float*)d_in[2];
  const int*   temp_y      = (const int*)d_in[3];
  const float* is_leaf     = (const float*)d_in[4];
  const float* W_gcn       = (const float*)d_in[5];
  const float* b_gcn       = (const float*)d_in[6];
  const float* Wx_zr       = (const float*)d_in[7];
  const float* Wh_zr       = (const float*)d_in[8];
  const float* b_zr        = (const float*)d_in[9];
  const float* Wx_c        = (const float*)d_in[10];
  const float* Wh_c        = (const float*)d_in[11];
  const float* b_c         = (const float*)d_in[12];
  const float* h_vecs      = (const float*)d_in[13];
  const float* W_leaf      = (const float*)d_in[14];
  const float* b_leaf      = (const float*)d_in[15];
  const float* W_conv      = (const float*)d_in[16];
  const float* b_conv      = (const float*)d_in[17];
  float* out = (float*)d_out;
  (void)in_sizes; (void)n_in; (void)out_size;

  const size_t NEED = 156000000;
  if (ws_size < NEED) {
    wsprobe<<<1, 64, 0, stream>>>(1000.f + (float)(ws_size >> 20), out);
    return;
  }

  char* ws = (char*)d_ws;
  size_t off = 0;
  auto alloc = [&](size_t bytes) -> void* {
    void* p = ws + off;
    off = (off + bytes + 255) & ~(size_t)255;
    return p;
  };
  bf16*   Whzrt = (bf16*)  alloc((size_t)1024 * 512 * 2);
  bf16*   Whct  = (bf16*)  alloc((size_t)512 * 512 * 2);
  bf16*   Wxzrt = (bf16*)  alloc((size_t)1024 * 512 * 2);
  bf16*   Wxct  = (bf16*)  alloc((size_t)512 * 512 * 2);
  bf16*   Wgt   = (bf16*)  alloc((size_t)256 * 128 * 2);
  bf16*   hfin  = (bf16*)  alloc((size_t)32768 * 512 * 2);  // 32 MB
  bf16*   xzrp  = (bf16*)  alloc((size_t)32768 * 1024 * 2); // 64 MB (bias folded)
  bf16*   xcp   = (bf16*)  alloc((size_t)32768 * 512 * 2);  // 32 MB (bias folded)
  bf16*   hsb   = (bf16*)  alloc((size_t)4096 * 512 * 2);
  bf16*   rhb   = (bf16*)  alloc((size_t)4096 * 512 * 2);
  __half* zh    = (__half*)alloc((size_t)4096 * 512 * 2);
  float*  lv    = (float*) alloc(4096 * 4);
  float*  hn    = (float*) alloc(4 * 512 * 4);
  float*  v     = (float*) alloc(4 * 512 * 4);
  float*  loffp = (float*) alloc(2048 * 4);
  bf16*   Htrb  = hfin;   // overlay: hfin dead after gemmx consumes it

  hipMemsetAsync(v, 0, 4 * 512 * 4, stream);

  prep<<<6272, 256, 0, stream>>>(Wh_zr, Wh_c, Wx_zr, Wx_c, W_gcn,
                                 Whzrt, Whct, Wxzrt, Wxct, Wgt);
  gcnk<<<dim3(256, 2, 2), 256, 0, stream>>>(x_graph, x_graph_inv, Wgt, b_gcn, hfin);
  gemmx<<<dim3(256, 12), 256, 0, stream>>>(hfin, Wxzrt, Wxct, b_zr, b_c, xzrp, xcp);

  // sequential GRU: 8-wave blocks (2 waves/SIMD), B from L2 with reg prefetch
  for (int t = 0; t < 8; ++t) {
    gruz<<<dim3(64, 4), 512, 0, stream>>>(hsb, Whzrt,
                                          xzrp + (size_t)t * 4096 * 1024,
                                          zh, rhb, t == 0);
    gruc<<<dim3(64, 4), 512, 0, stream>>>(rhb, Whct,
                                          xcp + (size_t)t * 4096 * 512,
                                          zh, hsb, t == 0);
  }

  norm_lvec<<<1025, 256, 0, stream>>>(hsb, W_leaf, b_leaf, h_vecs, Htrb, lv, hn);
  htf<<<64, 512, 0, stream>>>(Htrb, x_feature, W_conv, b_conv, lv, v);
  attk<<<1024, 256, 0, stream>>>(Htrb, v, out);
  loff<<<dim3(512, 4), 256, 0, stream>>>(Htrb, hn, temp_y, loffp);
  fini<<<1, 256, 0, stream>>>(loffp, lv, is_leaf, out);
}